// Round 8
// baseline (432.518 us; speedup 1.0000x reference)
//
#include <hip/hip_runtime.h>
#include <cmath>

// ---------------------------------------------------------------------------
// min_max_net: w' = weight with montn columns squared; y = x @ w'^T + bias;
// out[b] = (rand_u[b] < sigmoid(max_g min_{j in g} y[b, g*64+j])) ? 1 : 0
//
// R8: GEMM was LDS-BW-bound (80KB/block-iter vs ~85B/cyc/CU => ~102us floor).
// Move B (W) operand out of LDS: direct global->VGPR fragment loads (L2-
// resident per-XCD slice via swizzle), register double-buffered across the
// barrier (B loads fly through vmcnt(N) partial waits). A (X) keeps verified
// DMA staging + XOR swizzle. LDS traffic -40%.
// fp16 hi*hi GEMM (sigma ~3.6e-4), margin 4e-3, exact fp32 recompute of
// undecided rows (~16 expected, cap 96).
// ---------------------------------------------------------------------------

typedef _Float16 f16x8 __attribute__((ext_vector_type(8)));
typedef float f32x4 __attribute__((ext_vector_type(4)));

#define MARGIN_EPS 4e-3f
#define MAX_UNDEC 96

__device__ __forceinline__ void async_load16(const void* gptr, void* lptr) {
  __builtin_amdgcn_global_load_lds(
      (const __attribute__((address_space(1))) void*)gptr,
      (__attribute__((address_space(3))) void*)lptr, 16, 0, 0);
}

__device__ __forceinline__ float us2f(unsigned short u) {
  return (float)__builtin_bit_cast(_Float16, u);
}

// ---- kernel 1: in-place fp32 row -> [hi fp16 | lo fp16], 1 wave per row ----
__global__ void convert_split(float* __restrict__ x, float* __restrict__ wgt,
                              const int* __restrict__ montn,
                              int* __restrict__ count) {
  __shared__ unsigned msk[64];
  const int t = threadIdx.x, l = t & 63, w = t >> 6;
  const int r = blockIdx.x * 4 + w;
  const int use_mask = (r >= 8192) ? 1 : 0;   // block-uniform (4-row blocks)
  if (blockIdx.x == 0 && t == 0) *count = 0;
  if (use_mask) {
    if (t < 64) msk[t] = 0u;
    __syncthreads();
    for (int j = t; j < 512; j += 256) {
      const int c = montn[j];
      atomicOr(&msk[c >> 5], 1u << (c & 31));
    }
    __syncthreads();
  }
  float* rowp = use_mask ? (wgt + (size_t)(r - 8192) * 2048)
                         : (x + (size_t)r * 2048);
  float4 v[8];
#pragma unroll
  for (int j = 0; j < 8; ++j) v[j] = ((const float4*)rowp)[l + 64 * j];
  unsigned mw[8];
#pragma unroll
  for (int j = 0; j < 8; ++j)
    mw[j] = use_mask ? msk[(l >> 3) + 8 * j] : 0u;

  unsigned short* up = (unsigned short*)rowp;
#pragma unroll
  for (int j = 0; j < 8; ++j) {
    unsigned short hs[4], ls[4];
    const float* fv = (const float*)&v[j];
#pragma unroll
    for (int c = 0; c < 4; ++c) {
      float f = fv[c];
      if ((mw[j] >> (4 * (l & 7) + c)) & 1u) f = f * f;
      _Float16 h = (_Float16)f;          // RTNE
      float res = f - (float)h;          // exact in fp32
      _Float16 lo = (_Float16)res;
      hs[c] = __builtin_bit_cast(unsigned short, h);
      ls[c] = __builtin_bit_cast(unsigned short, lo);
    }
    uint2 H, L;
    H.x = (unsigned)hs[0] | ((unsigned)hs[1] << 16);
    H.y = (unsigned)hs[2] | ((unsigned)hs[3] << 16);
    L.x = (unsigned)ls[0] | ((unsigned)ls[1] << 16);
    L.y = (unsigned)ls[2] | ((unsigned)ls[3] << 16);
    *((uint2*)(up + 4 * l + 256 * j)) = H;           // hi plane [0,2048)
    *((uint2*)(up + 2048 + 4 * l + 256 * j)) = L;    // lo plane [2048,4096)
  }
}

// ---- kernel 2: hi*hi GEMM + fused bias/group-min ---------------------------
// Block 128x128, BK=64, 4 waves (2x2), wave 64x64 via 4x4 MFMA 16x16x32 f16.
// A: LDS DMA staging, 128B rows, chunk c stored at c^(row&7) (zero-conflict,
// verified R2/R3/R7). B: direct global->VGPR fragments, reg-dbuf'd; loads
// issued pre-barrier so they pipeline across it (vmcnt partial waits).
__global__ __launch_bounds__(256, 3) void gemm_minmax(
    const unsigned short* __restrict__ X, const unsigned short* __restrict__ W,
    const float* __restrict__ bias, float* __restrict__ gmins) {
  __shared__ unsigned short As[128 * 64];   // 16 KB
  const int t = threadIdx.x;
  const int lane = t & 63;
  const int w = t >> 6;
  const int wm = w >> 1, wn = w & 1;
  // XCD swizzle: grid 2048 = 64 m x 32 n; XCD (lin&7) owns a 4-wide n-slice.
  const int lin = blockIdx.x;
  const int sid = lin >> 3;
  const int m0 = (sid >> 2) * 128;
  const int n0 = ((lin & 7) * 4 + (sid & 3)) * 128;

  // A staging geometry (4 DMA calls/iter, verified layout)
  const int rowBase = w * 8 + (lane >> 3);
  const int gchunk = ((lane & 7) ^ ((lane >> 3) & 7)) * 8;  // ushort offset
  size_t sA[4];
  unsigned short* ldsA[4];
#pragma unroll
  for (int c = 0; c < 4; ++c) {
    sA[c] = (size_t)(m0 + c * 32 + rowBase) * 4096 + gchunk;
    ldsA[c] = As + c * 2048 + w * 512;  // wave-uniform base (ushort units)
  }

  const int am = lane & 15, quad = lane >> 4;
  int arow[4];
#pragma unroll
  for (int i = 0; i < 4; ++i) arow[i] = (wm * 64 + i * 16 + am) * 64;
  int swz[2];
#pragma unroll
  for (int h = 0; h < 2; ++h) swz[h] = (((h << 2) + quad) ^ (am & 7)) * 8;

  // B fragment pointers: row n0+wn*64+i*16+am, k-base quad*8 (+it*64+h*32)
  const unsigned short* bp[4];
#pragma unroll
  for (int i = 0; i < 4; ++i)
    bp[i] = W + (size_t)(n0 + wn * 64 + i * 16 + am) * 4096 + quad * 8;

  f32x4 acc[4][4];
#pragma unroll
  for (int i = 0; i < 4; ++i)
#pragma unroll
    for (int j = 0; j < 4; ++j) acc[i][j] = (f32x4){0.f, 0.f, 0.f, 0.f};

#define STAGE_A(IT)                                                    \
  {                                                                    \
    _Pragma("unroll") for (int c = 0; c < 4; ++c)                      \
        async_load16(X + sA[c] + (IT) * 64, ldsA[c]);                  \
  }
#define LOAD_B(BREG, IT)                                               \
  {                                                                    \
    _Pragma("unroll") for (int i = 0; i < 4; ++i) {                    \
      BREG[i][0] = *(const f16x8*)(bp[i] + (IT) * 64);                 \
      BREG[i][1] = *(const f16x8*)(bp[i] + (IT) * 64 + 32);            \
    }                                                                  \
  }
#define COMPUTE_STEP(BREG)                                             \
  {                                                                    \
    _Pragma("unroll") for (int h = 0; h < 2; ++h) {                    \
      f16x8 av[4];                                                     \
      _Pragma("unroll") for (int i = 0; i < 4; ++i)                    \
          av[i] = *(const f16x8*)(As + arow[i] + swz[h]);              \
      _Pragma("unroll") for (int mb = 0; mb < 4; ++mb)                 \
          _Pragma("unroll") for (int nb = 0; nb < 4; ++nb)             \
              acc[mb][nb] = __builtin_amdgcn_mfma_f32_16x16x32_f16(    \
                  av[mb], BREG[nb][h], acc[mb][nb], 0, 0, 0);          \
    }                                                                  \
  }

  f16x8 b0[4][2], b1[4][2];
  LOAD_B(b0, 0);

#pragma unroll 1
  for (int p = 0; p < 16; ++p) {
    const int it0 = 2 * p, it1 = 2 * p + 1;
    __syncthreads();           // prior compute's A ds_reads complete
    STAGE_A(it0);
    LOAD_B(b1, it1);           // flies across the barrier (no LDS dep)
    __syncthreads();           // A(it0) staged
    COMPUTE_STEP(b0);
    __syncthreads();
    STAGE_A(it1);
    if (p < 15) LOAD_B(b0, it1 + 1);
    __syncthreads();
    COMPUTE_STEP(b1);
  }
#undef STAGE_A
#undef LOAD_B
#undef COMPUTE_STEP

  // epilogue: bias + min over wave's 64 cols (one group) per row
  float bv4[4];
#pragma unroll
  for (int nb = 0; nb < 4; ++nb) bv4[nb] = bias[n0 + wn * 64 + nb * 16 + am];
  const int grp = (n0 >> 6) + wn;
#pragma unroll
  for (int mb = 0; mb < 4; ++mb) {
#pragma unroll
    for (int reg = 0; reg < 4; ++reg) {
      float v = fminf(fminf(acc[mb][0][reg] + bv4[0], acc[mb][1][reg] + bv4[1]),
                      fminf(acc[mb][2][reg] + bv4[2], acc[mb][3][reg] + bv4[3]));
      v = fminf(v, __shfl_xor(v, 1, 64));
      v = fminf(v, __shfl_xor(v, 2, 64));
      v = fminf(v, __shfl_xor(v, 4, 64));
      v = fminf(v, __shfl_xor(v, 8, 64));
      if (am == 0) {
        const int row = m0 + wm * 64 + mb * 16 + quad * 4 + reg;
        gmins[(size_t)row * 64 + grp] = v;
      }
    }
  }
}

// ---- kernel 3: max over groups -> margin test (+ ybuf zeroing) -------------
__global__ void finalize_margin(const float* __restrict__ gmins,
                                const float* __restrict__ rand_u,
                                float* __restrict__ out,
                                int* __restrict__ count, int* __restrict__ undec,
                                float4* __restrict__ ybuf4) {
  if (blockIdx.x < 384)  // zero ybuf: 384*256 float4 = 96*4096 floats
    ybuf4[(size_t)blockIdx.x * 256 + threadIdx.x] = (float4){0.f, 0.f, 0.f, 0.f};
  const int wv = threadIdx.x >> 6, lane = threadIdx.x & 63;
  const int row = blockIdx.x * 4 + wv;
  float v = gmins[(size_t)row * 64 + lane];
  v = fmaxf(v, __shfl_xor(v, 1, 64));
  v = fmaxf(v, __shfl_xor(v, 2, 64));
  v = fmaxf(v, __shfl_xor(v, 4, 64));
  v = fmaxf(v, __shfl_xor(v, 8, 64));
  v = fmaxf(v, __shfl_xor(v, 16, 64));
  v = fmaxf(v, __shfl_xor(v, 32, 64));
  if (lane == 0) {
    const float u = rand_u[row];
    const float slo = 1.0f / (1.0f + expf(-(v - MARGIN_EPS)));
    const float shi = 1.0f / (1.0f + expf(-(v + MARGIN_EPS)));
    if (u < slo) {
      out[row] = 1.0f;
    } else if (u >= shi) {
      out[row] = 0.0f;
    } else {
      const int i = atomicAdd(count, 1);
      if (i < 8192) undec[i] = row;
    }
  }
}

// ---- kernel 4: exact fp32 recompute, W read ONCE ---------------------------
__global__ __launch_bounds__(256) void recompute_rows(
    const unsigned short* __restrict__ X, const unsigned short* __restrict__ W,
    const int* __restrict__ count, const int* __restrict__ undec,
    float* __restrict__ ybuf) {
  __shared__ float wf[64 * 129];   // ~33 KB
  __shared__ float part[256];
  const int g = blockIdx.x, kc = blockIdx.y;
  const int t = threadIdx.x;
  int n = *count;
  if (n > MAX_UNDEC) n = MAX_UNDEC;
  if (n == 0) return;

  {  // stage: thread t -> col t>>2, k-segment t&3 (32 k each)
    const int cl = t >> 2, ks = t & 3;
    const unsigned short* wp =
        W + (size_t)(g * 64 + cl) * 4096 + kc * 128 + ks * 32;
    float* dst = wf + cl * 129 + ks * 32;
#pragma unroll
    for (int i = 0; i < 32; i += 8) {
      uint4 hv = *(const uint4*)(wp + i);
      uint4 lv = *(const uint4*)(wp + 2048 + i);
      const unsigned* hw = (const unsigned*)&hv;
      const unsigned* lw = (const unsigned*)&lv;
#pragma unroll
      for (int m = 0; m < 4; ++m) {
        dst[i + 2 * m] = us2f((unsigned short)(hw[m] & 0xFFFF)) +
                         us2f((unsigned short)(lw[m] & 0xFFFF));
        dst[i + 2 * m + 1] = us2f((unsigned short)(hw[m] >> 16)) +
                             us2f((unsigned short)(lw[m] >> 16));
      }
    }
  }
  __syncthreads();

  const int col = t & 63, kq = t >> 6;   // 32 k per quarter
  const float* wcol = wf + col * 129 + kq * 32;
  for (int s = 0; s < n; ++s) {
    const int row = undec[s];
    const unsigned short* xp = X + (size_t)row * 4096 + kc * 128 + kq * 32;
    float acc = 0.f;
#pragma unroll
    for (int i = 0; i < 32; i += 8) {
      uint4 hv = *(const uint4*)(xp + i);
      uint4 lv = *(const uint4*)(xp + 2048 + i);
      const unsigned* hw = (const unsigned*)&hv;
      const unsigned* lw = (const unsigned*)&lv;
#pragma unroll
      for (int m = 0; m < 4; ++m) {
        const float x0 = us2f((unsigned short)(hw[m] & 0xFFFF)) +
                         us2f((unsigned short)(lw[m] & 0xFFFF));
        const float x1 = us2f((unsigned short)(hw[m] >> 16)) +
                         us2f((unsigned short)(lw[m] >> 16));
        acc = fmaf(x0, wcol[i + 2 * m], acc);
        acc = fmaf(x1, wcol[i + 2 * m + 1], acc);
      }
    }
    part[t] = acc;
    __syncthreads();
    if (t < 64) {
      const float y = part[t] + part[t + 64] + part[t + 128] + part[t + 192];
      atomicAdd(ybuf + (size_t)s * 4096 + g * 64 + t, y);
    }
    __syncthreads();
  }
}

// ---- kernel 5: final decision for undecided rows ---------------------------
__global__ void decide(const float* __restrict__ ybuf,
                       const int* __restrict__ undec, const int* __restrict__ count,
                       const float* __restrict__ bias,
                       const float* __restrict__ rand_u, float* __restrict__ out) {
  __shared__ float gm[64];
  int n = *count;
  if (n > MAX_UNDEC) n = MAX_UNDEC;
  const int s = blockIdx.x;
  if (s >= n) return;
  const int t = threadIdx.x;
  const int g = t >> 2, p4 = t & 3;
  const float* yb = ybuf + (size_t)s * 4096;
  const int c0 = g * 64 + p4 * 16;
  float m = 3.4e38f;
#pragma unroll
  for (int e = 0; e < 16; ++e) m = fminf(m, yb[c0 + e] + bias[c0 + e]);
  m = fminf(m, __shfl_xor(m, 1, 64));
  m = fminf(m, __shfl_xor(m, 2, 64));
  if (p4 == 0) gm[g] = m;
  __syncthreads();
  if (t < 64) {
    float v = gm[t];
    v = fmaxf(v, __shfl_xor(v, 1, 64));
    v = fmaxf(v, __shfl_xor(v, 2, 64));
    v = fmaxf(v, __shfl_xor(v, 4, 64));
    v = fmaxf(v, __shfl_xor(v, 8, 64));
    v = fmaxf(v, __shfl_xor(v, 16, 64));
    v = fmaxf(v, __shfl_xor(v, 32, 64));
    if (t == 0) {
      const int row = undec[s];
      const float sg = 1.0f / (1.0f + expf(-v));
      out[row] = (rand_u[row] < sg) ? 1.0f : 0.0f;
    }
  }
}

extern "C" void kernel_launch(void* const* d_in, const int* in_sizes, int n_in,
                              void* d_out, int out_size, void* d_ws, size_t ws_size,
                              hipStream_t stream) {
  float* x = (float*)d_in[0];           // [8192, 2048] fp32 (mutated in place)
  float* weight = (float*)d_in[1];      // [4096, 2048] fp32 (mutated in place)
  const float* bias = (const float*)d_in[2];
  const float* rand_u = (const float*)d_in[3];
  const int* montn = (const int*)d_in[4];
  float* out = (float*)d_out;

  char* ws = (char*)d_ws;
  int* count = (int*)ws;                         // 4 B
  int* undec = (int*)(ws + 256);                 // 32 KB
  float* ybuf = (float*)(ws + 65536);            // 96*4096*4 = 1.5 MB
  float* gmins = (float*)(ws + 65536 + 1572864); // 2 MB

  convert_split<<<3072, 256, 0, stream>>>(x, weight, montn, count);
  gemm_minmax<<<2048, 256, 0, stream>>>(
      (const unsigned short*)x, (const unsigned short*)weight, bias, gmins);
  finalize_margin<<<2048, 256, 0, stream>>>(gmins, rand_u, out, count, undec,
                                            (float4*)ybuf);
  recompute_rows<<<dim3(64, 16), 256, 0, stream>>>(
      (const unsigned short*)x, (const unsigned short*)weight, count, undec, ybuf);
  decide<<<MAX_UNDEC, 256, 0, stream>>>(ybuf, undec, count, bias, rand_u, out);
}

// Round 9
// 284.381 us; speedup vs baseline: 1.5209x; 1.5209x over previous
//
#include <hip/hip_runtime.h>
#include <cmath>

// ---------------------------------------------------------------------------
// min_max_net: w' = weight with montn columns squared; y = x @ w'^T + bias;
// out[b] = (rand_u[b] < sigmoid(max_g min_{j in g} y[b, g*64+j])) ? 1 : 0
//
// R9: GEMM = R4's verified 128x256 body (BK=64, 4x8 wave tile, 32 MFMA per
// barrier pair, XOR-swizzled LDS, zero conflicts, 127us measured) + XCD
// n-slice swizzle (grid 1024; per-XCD W-hi slice 2MB, L2-resident).
// R8's direct-global B loads reverted (16 cache lines/instr scatter).
// Convert: all-16B lane accesses (loads-then-stores, in-wave order safe).
// fp16 hi*hi GEMM (sigma ~3.6e-4), margin 4e-3, exact fp32 recompute of
// undecided rows (~16 expected, cap 96).
// ---------------------------------------------------------------------------

typedef _Float16 f16x8 __attribute__((ext_vector_type(8)));
typedef float f32x4 __attribute__((ext_vector_type(4)));

#define MARGIN_EPS 4e-3f
#define MAX_UNDEC 96

__device__ __forceinline__ void async_load16(const void* gptr, void* lptr) {
  __builtin_amdgcn_global_load_lds(
      (const __attribute__((address_space(1))) void*)gptr,
      (__attribute__((address_space(3))) void*)lptr, 16, 0, 0);
}

__device__ __forceinline__ float us2f(unsigned short u) {
  return (float)__builtin_bit_cast(_Float16, u);
}

// ---- kernel 1: in-place fp32 row -> [hi fp16 | lo fp16], 1 wave per row ----
// Lane l owns floats [8l, 8l+8) of each 512-float pass: 2x float4 loads,
// uint4 (16B) hi/lo stores. ALL loads precede ALL stores (in-place safety:
// pass-q lo-stores overlap pass-p>q load ranges).
__global__ void convert_split(float* __restrict__ x, float* __restrict__ wgt,
                              const int* __restrict__ montn,
                              int* __restrict__ count) {
  __shared__ unsigned msk[64];
  const int t = threadIdx.x, l = t & 63, w = t >> 6;
  const int r = blockIdx.x * 4 + w;
  const int use_mask = (r >= 8192) ? 1 : 0;   // block-uniform (4-row blocks)
  if (blockIdx.x == 0 && t == 0) *count = 0;
  if (use_mask) {
    if (t < 64) msk[t] = 0u;
    __syncthreads();
    for (int j = t; j < 512; j += 256) {
      const int c = montn[j];
      atomicOr(&msk[c >> 5], 1u << (c & 31));
    }
    __syncthreads();
  }
  float* rowp = use_mask ? (wgt + (size_t)(r - 8192) * 2048)
                         : (x + (size_t)r * 2048);
  float4 v[4][2];
#pragma unroll
  for (int p = 0; p < 4; ++p) {
    v[p][0] = ((const float4*)rowp)[p * 128 + 2 * l];
    v[p][1] = ((const float4*)rowp)[p * 128 + 2 * l + 1];
  }
  unsigned mw[4];
#pragma unroll
  for (int p = 0; p < 4; ++p)
    mw[p] = use_mask ? msk[p * 16 + (l >> 2)] : 0u;

  unsigned short* up = (unsigned short*)rowp;
#pragma unroll
  for (int p = 0; p < 4; ++p) {
    float f[8];
    f[0] = v[p][0].x; f[1] = v[p][0].y; f[2] = v[p][0].z; f[3] = v[p][0].w;
    f[4] = v[p][1].x; f[5] = v[p][1].y; f[6] = v[p][1].z; f[7] = v[p][1].w;
    unsigned short hs[8], ls[8];
#pragma unroll
    for (int c = 0; c < 8; ++c) {
      float g = f[c];
      if ((mw[p] >> (8 * (l & 3) + c)) & 1u) g = g * g;
      _Float16 h = (_Float16)g;          // RTNE
      float res = g - (float)h;          // exact in fp32
      _Float16 lo = (_Float16)res;
      hs[c] = __builtin_bit_cast(unsigned short, h);
      ls[c] = __builtin_bit_cast(unsigned short, lo);
    }
    uint4 H, L;
    H.x = (unsigned)hs[0] | ((unsigned)hs[1] << 16);
    H.y = (unsigned)hs[2] | ((unsigned)hs[3] << 16);
    H.z = (unsigned)hs[4] | ((unsigned)hs[5] << 16);
    H.w = (unsigned)hs[6] | ((unsigned)hs[7] << 16);
    L.x = (unsigned)ls[0] | ((unsigned)ls[1] << 16);
    L.y = (unsigned)ls[2] | ((unsigned)ls[3] << 16);
    L.z = (unsigned)ls[4] | ((unsigned)ls[5] << 16);
    L.w = (unsigned)ls[6] | ((unsigned)ls[7] << 16);
    *((uint4*)(up + p * 512 + 8 * l)) = H;            // hi plane [0,2048)
    *((uint4*)(up + 2048 + p * 512 + 8 * l)) = L;     // lo plane [2048,4096)
  }
}

// ---- kernel 2: hi*hi GEMM + fused bias/group-min ---------------------------
// R4's verified body: block 128x256, BK=64, 4 waves (2x2), wave 64x128 via
// 4x8 MFMA 16x16x32 f16. XOR-swizzled LDS (zero conflicts measured).
// XCD swizzle: grid 1024 = 64 m x 16 n; XCD (lin&7) owns a 2-wide n-slice.
__global__ __launch_bounds__(256, 2) void gemm_minmax(
    const unsigned short* __restrict__ X, const unsigned short* __restrict__ W,
    const float* __restrict__ bias, float* __restrict__ gmins) {
  __shared__ unsigned short As[128 * 64];   // 16 KB
  __shared__ unsigned short Bs[256 * 64];   // 32 KB
  const int t = threadIdx.x;
  const int lane = t & 63;
  const int w = t >> 6;
  const int wm = w >> 1, wn = w & 1;
  const int lin = blockIdx.x;
  const int sid = lin >> 3;
  const int m0 = (sid >> 1) * 128;
  const int n0 = ((lin & 7) * 2 + (sid & 1)) * 256;

  // staging: call c covers rows [c*32, c*32+32); lane row = c*32+w*8+(l>>3),
  // stored chunk l&7 holds global chunk (l&7)^(row&7).
  const int rowBase = w * 8 + (lane >> 3);
  const int gchunk = ((lane & 7) ^ ((lane >> 3) & 7)) * 8;  // ushort offset
  const size_t gA0 = (size_t)(m0 + rowBase) * 4096 + gchunk;
  const size_t gB0 = (size_t)(n0 + rowBase) * 4096 + gchunk;
  unsigned short* ldsA0 = As + w * 512;   // wave-uniform base (ushort units)
  unsigned short* ldsB0 = Bs + w * 512;

  const int am = lane & 15, quad = lane >> 4;
  int arow[4], brow[8];
#pragma unroll
  for (int i = 0; i < 4; ++i) arow[i] = (wm * 64 + i * 16 + am) * 64;
#pragma unroll
  for (int j = 0; j < 8; ++j) brow[j] = (wn * 128 + j * 16 + am) * 64;
  int swz[2];
#pragma unroll
  for (int h = 0; h < 2; ++h) swz[h] = (((h << 2) + quad) ^ (am & 7)) * 8;

  f32x4 acc[4][8];
#pragma unroll
  for (int i = 0; i < 4; ++i)
#pragma unroll
    for (int j = 0; j < 8; ++j) acc[i][j] = (f32x4){0.f, 0.f, 0.f, 0.f};

#pragma unroll 1
  for (int it = 0; it < 32; ++it) {
    const int kin = it * 64;
    __syncthreads();  // previous iteration's LDS reads complete
#pragma unroll
    for (int c = 0; c < 4; ++c)
      async_load16(X + gA0 + (size_t)c * (32 * 4096) + kin, ldsA0 + c * 2048);
#pragma unroll
    for (int c = 0; c < 8; ++c)
      async_load16(W + gB0 + (size_t)c * (32 * 4096) + kin, ldsB0 + c * 2048);
    __syncthreads();  // staging complete (drains vmcnt)

#pragma unroll
    for (int h = 0; h < 2; ++h) {
      f16x8 av[4], bv[8];
#pragma unroll
      for (int i = 0; i < 4; ++i) av[i] = *(const f16x8*)(As + arow[i] + swz[h]);
#pragma unroll
      for (int j = 0; j < 8; ++j) bv[j] = *(const f16x8*)(Bs + brow[j] + swz[h]);
#pragma unroll
      for (int mb = 0; mb < 4; ++mb)
#pragma unroll
        for (int nb = 0; nb < 8; ++nb)
          acc[mb][nb] = __builtin_amdgcn_mfma_f32_16x16x32_f16(
              av[mb], bv[nb], acc[mb][nb], 0, 0, 0);
    }
  }

  // epilogue: bias + per-group (64-col) min; wave covers 2 groups.
  float bv8[8];
#pragma unroll
  for (int nb = 0; nb < 8; ++nb) bv8[nb] = bias[n0 + wn * 128 + nb * 16 + am];
#pragma unroll
  for (int hh = 0; hh < 2; ++hh) {
    const int grp = (n0 >> 6) + wn * 2 + hh;
#pragma unroll
    for (int mb = 0; mb < 4; ++mb) {
#pragma unroll
      for (int reg = 0; reg < 4; ++reg) {
        float v = fminf(
            fminf(acc[mb][4 * hh + 0][reg] + bv8[4 * hh + 0],
                  acc[mb][4 * hh + 1][reg] + bv8[4 * hh + 1]),
            fminf(acc[mb][4 * hh + 2][reg] + bv8[4 * hh + 2],
                  acc[mb][4 * hh + 3][reg] + bv8[4 * hh + 3]));
        v = fminf(v, __shfl_xor(v, 1, 64));
        v = fminf(v, __shfl_xor(v, 2, 64));
        v = fminf(v, __shfl_xor(v, 4, 64));
        v = fminf(v, __shfl_xor(v, 8, 64));
        if (am == 0) {
          const int row = m0 + wm * 64 + mb * 16 + quad * 4 + reg;
          gmins[(size_t)row * 64 + grp] = v;
        }
      }
    }
  }
}

// ---- kernel 3: max over groups -> margin test (+ ybuf zeroing) -------------
__global__ void finalize_margin(const float* __restrict__ gmins,
                                const float* __restrict__ rand_u,
                                float* __restrict__ out,
                                int* __restrict__ count, int* __restrict__ undec,
                                float4* __restrict__ ybuf4) {
  if (blockIdx.x < 384)  // zero ybuf: 384*256 float4 = 96*4096 floats
    ybuf4[(size_t)blockIdx.x * 256 + threadIdx.x] = (float4){0.f, 0.f, 0.f, 0.f};
  const int wv = threadIdx.x >> 6, lane = threadIdx.x & 63;
  const int row = blockIdx.x * 4 + wv;
  float v = gmins[(size_t)row * 64 + lane];
  v = fmaxf(v, __shfl_xor(v, 1, 64));
  v = fmaxf(v, __shfl_xor(v, 2, 64));
  v = fmaxf(v, __shfl_xor(v, 4, 64));
  v = fmaxf(v, __shfl_xor(v, 8, 64));
  v = fmaxf(v, __shfl_xor(v, 16, 64));
  v = fmaxf(v, __shfl_xor(v, 32, 64));
  if (lane == 0) {
    const float u = rand_u[row];
    const float slo = 1.0f / (1.0f + expf(-(v - MARGIN_EPS)));
    const float shi = 1.0f / (1.0f + expf(-(v + MARGIN_EPS)));
    if (u < slo) {
      out[row] = 1.0f;
    } else if (u >= shi) {
      out[row] = 0.0f;
    } else {
      const int i = atomicAdd(count, 1);
      if (i < 8192) undec[i] = row;
    }
  }
}

// ---- kernel 4: exact fp32 recompute, W read ONCE ---------------------------
__global__ __launch_bounds__(256) void recompute_rows(
    const unsigned short* __restrict__ X, const unsigned short* __restrict__ W,
    const int* __restrict__ count, const int* __restrict__ undec,
    float* __restrict__ ybuf) {
  __shared__ float wf[64 * 129];   // ~33 KB
  __shared__ float part[256];
  const int g = blockIdx.x, kc = blockIdx.y;
  const int t = threadIdx.x;
  int n = *count;
  if (n > MAX_UNDEC) n = MAX_UNDEC;
  if (n == 0) return;

  {  // stage: thread t -> col t>>2, k-segment t&3 (32 k each)
    const int cl = t >> 2, ks = t & 3;
    const unsigned short* wp =
        W + (size_t)(g * 64 + cl) * 4096 + kc * 128 + ks * 32;
    float* dst = wf + cl * 129 + ks * 32;
#pragma unroll
    for (int i = 0; i < 32; i += 8) {
      uint4 hv = *(const uint4*)(wp + i);
      uint4 lv = *(const uint4*)(wp + 2048 + i);
      const unsigned* hw = (const unsigned*)&hv;
      const unsigned* lw = (const unsigned*)&lv;
#pragma unroll
      for (int m = 0; m < 4; ++m) {
        dst[i + 2 * m] = us2f((unsigned short)(hw[m] & 0xFFFF)) +
                         us2f((unsigned short)(lw[m] & 0xFFFF));
        dst[i + 2 * m + 1] = us2f((unsigned short)(hw[m] >> 16)) +
                             us2f((unsigned short)(lw[m] >> 16));
      }
    }
  }
  __syncthreads();

  const int col = t & 63, kq = t >> 6;   // 32 k per quarter
  const float* wcol = wf + col * 129 + kq * 32;
  for (int s = 0; s < n; ++s) {
    const int row = undec[s];
    const unsigned short* xp = X + (size_t)row * 4096 + kc * 128 + kq * 32;
    float acc = 0.f;
#pragma unroll
    for (int i = 0; i < 32; i += 8) {
      uint4 hv = *(const uint4*)(xp + i);
      uint4 lv = *(const uint4*)(xp + 2048 + i);
      const unsigned* hw = (const unsigned*)&hv;
      const unsigned* lw = (const unsigned*)&lv;
#pragma unroll
      for (int m = 0; m < 4; ++m) {
        const float x0 = us2f((unsigned short)(hw[m] & 0xFFFF)) +
                         us2f((unsigned short)(lw[m] & 0xFFFF));
        const float x1 = us2f((unsigned short)(hw[m] >> 16)) +
                         us2f((unsigned short)(lw[m] >> 16));
        acc = fmaf(x0, wcol[i + 2 * m], acc);
        acc = fmaf(x1, wcol[i + 2 * m + 1], acc);
      }
    }
    part[t] = acc;
    __syncthreads();
    if (t < 64) {
      const float y = part[t] + part[t + 64] + part[t + 128] + part[t + 192];
      atomicAdd(ybuf + (size_t)s * 4096 + g * 64 + t, y);
    }
    __syncthreads();
  }
}

// ---- kernel 5: final decision for undecided rows ---------------------------
__global__ void decide(const float* __restrict__ ybuf,
                       const int* __restrict__ undec, const int* __restrict__ count,
                       const float* __restrict__ bias,
                       const float* __restrict__ rand_u, float* __restrict__ out) {
  __shared__ float gm[64];
  int n = *count;
  if (n > MAX_UNDEC) n = MAX_UNDEC;
  const int s = blockIdx.x;
  if (s >= n) return;
  const int t = threadIdx.x;
  const int g = t >> 2, p4 = t & 3;
  const float* yb = ybuf + (size_t)s * 4096;
  const int c0 = g * 64 + p4 * 16;
  float m = 3.4e38f;
#pragma unroll
  for (int e = 0; e < 16; ++e) m = fminf(m, yb[c0 + e] + bias[c0 + e]);
  m = fminf(m, __shfl_xor(m, 1, 64));
  m = fminf(m, __shfl_xor(m, 2, 64));
  if (p4 == 0) gm[g] = m;
  __syncthreads();
  if (t < 64) {
    float v = gm[t];
    v = fmaxf(v, __shfl_xor(v, 1, 64));
    v = fmaxf(v, __shfl_xor(v, 2, 64));
    v = fmaxf(v, __shfl_xor(v, 4, 64));
    v = fmaxf(v, __shfl_xor(v, 8, 64));
    v = fmaxf(v, __shfl_xor(v, 16, 64));
    v = fmaxf(v, __shfl_xor(v, 32, 64));
    if (t == 0) {
      const int row = undec[s];
      const float sg = 1.0f / (1.0f + expf(-v));
      out[row] = (rand_u[row] < sg) ? 1.0f : 0.0f;
    }
  }
}

extern "C" void kernel_launch(void* const* d_in, const int* in_sizes, int n_in,
                              void* d_out, int out_size, void* d_ws, size_t ws_size,
                              hipStream_t stream) {
  float* x = (float*)d_in[0];           // [8192, 2048] fp32 (mutated in place)
  float* weight = (float*)d_in[1];      // [4096, 2048] fp32 (mutated in place)
  const float* bias = (const float*)d_in[2];
  const float* rand_u = (const float*)d_in[3];
  const int* montn = (const int*)d_in[4];
  float* out = (float*)d_out;

  char* ws = (char*)d_ws;
  int* count = (int*)ws;                         // 4 B
  int* undec = (int*)(ws + 256);                 // 32 KB
  float* ybuf = (float*)(ws + 65536);            // 96*4096*4 = 1.5 MB
  float* gmins = (float*)(ws + 65536 + 1572864); // 2 MB

  convert_split<<<3072, 256, 0, stream>>>(x, weight, montn, count);
  gemm_minmax<<<1024, 256, 0, stream>>>(
      (const unsigned short*)x, (const unsigned short*)weight, bias, gmins);
  finalize_margin<<<2048, 256, 0, stream>>>(gmins, rand_u, out, count, undec,
                                            (float4*)ybuf);
  recompute_rows<<<dim3(64, 16), 256, 0, stream>>>(
      (const unsigned short*)x, (const unsigned short*)weight, count, undec, ybuf);
  decide<<<MAX_UNDEC, 256, 0, stream>>>(ybuf, undec, count, bias, rand_u, out);
}